// Round 3
// baseline (395.950 us; speedup 1.0000x reference)
//
#include <hip/hip_runtime.h>
#include <stdint.h>

// Q8_0-style dequant + linear. HARNESS DTYPES (R2 post-mortem): reference is
// float16, which the harness upcasts to FLOAT32. So x/scales/bias are
// const float*, out is float*. q_weight is int32.
//   W[o,k] = (q[o,k]-128) * scales[o,k/32]
//   out[m,o] = sum_k x[m,k]*W[o,k] + bias[o]   (bf16 MFMA, fp32 accum/out)
// M = 4096, N = O = 4096, K = 4096.

#define QOFF 128

typedef __bf16 bf16_t;
typedef __bf16 bf16x8 __attribute__((ext_vector_type(8)));
typedef float f32x4 __attribute__((ext_vector_type(4)));

// ---------------------------------------------------------------------------
// Pass 1a: x fp32 -> bf16 (for MFMA A operand).
// ---------------------------------------------------------------------------
__global__ __launch_bounds__(256) void cvt_kernel(const float* __restrict__ X,
                                                  bf16_t* __restrict__ Xb) {
  const size_t e = ((size_t)blockIdx.x * 256 + threadIdx.x) * 8;
  float4 a = *(const float4*)(X + e);
  float4 b = *(const float4*)(X + e + 4);
  bf16x8 t;
  t[0] = (bf16_t)a.x; t[1] = (bf16_t)a.y; t[2] = (bf16_t)a.z; t[3] = (bf16_t)a.w;
  t[4] = (bf16_t)b.x; t[5] = (bf16_t)b.y; t[6] = (bf16_t)b.z; t[7] = (bf16_t)b.w;
  *(bf16x8*)(Xb + e) = t;
}

// ---------------------------------------------------------------------------
// Pass 1b: dequant q (int32 [O,K]) + scales (fp32 [O,NB]) -> bf16 W [O,K].
// 8 consecutive elems/thread; never straddles a 32-elem scale block.
// ---------------------------------------------------------------------------
__global__ __launch_bounds__(256) void dequant_kernel(
    const int* __restrict__ q, const float* __restrict__ scales,
    bf16_t* __restrict__ W, int K, int NB) {
  const size_t e = ((size_t)blockIdx.x * 256 + threadIdx.x) * 8;
  const int o = (int)(e / (size_t)K);
  const int i = (int)(e % (size_t)K);
  const float s = scales[o * NB + (i >> 5)];

  int4 a = *(const int4*)(q + e);
  int4 b = *(const int4*)(q + e + 4);
  const int* av = (const int*)&a;
  const int* bv = (const int*)&b;

  bf16x8 t;
#pragma unroll
  for (int j = 0; j < 4; ++j) t[j] = (bf16_t)((float)(av[j] - QOFF) * s);
#pragma unroll
  for (int j = 0; j < 4; ++j) t[4 + j] = (bf16_t)((float)(bv[j] - QOFF) * s);

  *(bf16x8*)(W + e) = t;
}

// ---------------------------------------------------------------------------
// Pass 2: 128x128 tile bf16 GEMM, B^T layout ([N,K] row-major), BK=32.
// 256 threads = 4 waves (2x2); each wave owns 64x64 = 4x4 frags of 16x16,
// mfma_f32_16x16x32_bf16. Register staging -> LDS (m93-class; safe).
// MODE 0: A,B both pre-converted bf16 in ws.
// MODE 1: A fp32 converted inline; B bf16 in ws.
// MODE 2: fully fused (A fp32 inline; B dequant inline).
// ---------------------------------------------------------------------------
template <int MODE>
__global__ __launch_bounds__(256) void gemm_bt(
    const bf16_t* __restrict__ Ab, const float* __restrict__ Af,
    const bf16_t* __restrict__ Wb, const int* __restrict__ q,
    const float* __restrict__ scales, const float* __restrict__ bias,
    float* __restrict__ C, int M, int N, int K, int NB) {
  __shared__ bf16_t lsA[128 * 32];
  __shared__ bf16_t lsB[128 * 32];

  const int tid = threadIdx.x;
  const int lane = tid & 63;
  const int wave = tid >> 6;
  const int m0 = blockIdx.y * 128;
  const int n0 = blockIdx.x * 128;
  const int wm = (wave >> 1) * 64;
  const int wn = (wave & 1) * 64;
  const int r = lane & 15;   // fragment m (A) / n (B) index
  const int qd = lane >> 4;  // quad: k-group for inputs, row-group for C/D

  // Staging: 128x32 tile = 4096 elems; each thread owns 16 contiguous elems.
  const int e = tid * 16;
  const int row = e >> 5;  // tid/2
  const int col = e & 31;  // 0 or 16

  const bf16_t* gAb = (MODE == 0) ? Ab + (size_t)(m0 + row) * K + col : nullptr;
  const float* gAf = (MODE != 0) ? Af + (size_t)(m0 + row) * K + col : nullptr;
  const bf16_t* gW =
      (MODE != 2) ? Wb + (size_t)(n0 + row) * K + col : nullptr;
  const int* gQ = (MODE == 2) ? q + (size_t)(n0 + row) * K + col : nullptr;
  const float* gS = (MODE == 2) ? scales + (size_t)(n0 + row) * NB : nullptr;

  f32x4 acc[4][4] = {};

  for (int k0 = 0; k0 < K; k0 += 32) {
    bf16x8 a0, a1, b0, b1;
    if (MODE == 0) {
      a0 = *(const bf16x8*)(gAb + k0);
      a1 = *(const bf16x8*)(gAb + k0 + 8);
    } else {
      float4 f0 = *(const float4*)(gAf + k0);
      float4 f1 = *(const float4*)(gAf + k0 + 4);
      float4 f2 = *(const float4*)(gAf + k0 + 8);
      float4 f3 = *(const float4*)(gAf + k0 + 12);
      a0[0] = (bf16_t)f0.x; a0[1] = (bf16_t)f0.y; a0[2] = (bf16_t)f0.z; a0[3] = (bf16_t)f0.w;
      a0[4] = (bf16_t)f1.x; a0[5] = (bf16_t)f1.y; a0[6] = (bf16_t)f1.z; a0[7] = (bf16_t)f1.w;
      a1[0] = (bf16_t)f2.x; a1[1] = (bf16_t)f2.y; a1[2] = (bf16_t)f2.z; a1[3] = (bf16_t)f2.w;
      a1[4] = (bf16_t)f3.x; a1[5] = (bf16_t)f3.y; a1[6] = (bf16_t)f3.z; a1[7] = (bf16_t)f3.w;
    }
    if (MODE != 2) {
      b0 = *(const bf16x8*)(gW + k0);
      b1 = *(const bf16x8*)(gW + k0 + 8);
    } else {
      const float s = gS[k0 >> 5];  // one scale per row per BK=32 tile
      int qv[16];
      *(int4*)&qv[0] = *(const int4*)(gQ + k0);
      *(int4*)&qv[4] = *(const int4*)(gQ + k0 + 4);
      *(int4*)&qv[8] = *(const int4*)(gQ + k0 + 8);
      *(int4*)&qv[12] = *(const int4*)(gQ + k0 + 12);
#pragma unroll
      for (int j = 0; j < 8; ++j) b0[j] = (bf16_t)((float)(qv[j] - QOFF) * s);
#pragma unroll
      for (int j = 0; j < 8; ++j)
        b1[j] = (bf16_t)((float)(qv[8 + j] - QOFF) * s);
    }

    __syncthreads();  // previous iteration's LDS reads complete
    *(bf16x8*)&lsA[e] = a0;
    *(bf16x8*)&lsA[e + 8] = a1;
    *(bf16x8*)&lsB[e] = b0;
    *(bf16x8*)&lsB[e + 8] = b1;
    __syncthreads();  // staged tile visible to all waves

    bf16x8 af[4], bfv[4];
#pragma unroll
    for (int i = 0; i < 4; ++i) {
      // A-frag: lane holds A[m = r][k = qd*8 + j] -> contiguous 8 bf16
      af[i] = *(const bf16x8*)&lsA[(wm + i * 16 + r) * 32 + qd * 8];
      // B-frag (B^T rows): lane holds W[n = r][k = qd*8 + j]
      bfv[i] = *(const bf16x8*)&lsB[(wn + i * 16 + r) * 32 + qd * 8];
    }
#pragma unroll
    for (int mi = 0; mi < 4; ++mi)
#pragma unroll
      for (int ni = 0; ni < 4; ++ni)
        acc[mi][ni] = __builtin_amdgcn_mfma_f32_16x16x32_bf16(
            af[mi], bfv[ni], acc[mi][ni], 0, 0, 0);
  }

  // Epilogue: C/D mapping col = lane&15 (n), row = qd*4 + reg (m). fp32 out.
#pragma unroll
  for (int ni = 0; ni < 4; ++ni) {
    const int n = n0 + wn + ni * 16 + r;
    const float bv = bias[n];
#pragma unroll
    for (int mi = 0; mi < 4; ++mi) {
      const int mbase = m0 + wm + mi * 16 + qd * 4;
#pragma unroll
      for (int reg = 0; reg < 4; ++reg) {
        C[(size_t)(mbase + reg) * N + n] = acc[mi][ni][reg] + bv;
      }
    }
  }
}

// ---------------------------------------------------------------------------
extern "C" void kernel_launch(void* const* d_in, const int* in_sizes, int n_in,
                              void* d_out, int out_size, void* d_ws,
                              size_t ws_size, hipStream_t stream) {
  const float* x = (const float*)d_in[0];       // [M, K] fp32 (f16 upcast)
  const int* qw = (const int*)d_in[1];          // [O, K] int32
  const float* scales = (const float*)d_in[2];  // [O, NB] fp32
  const float* bias = (const float*)d_in[3];    // [O] fp32
  float* out = (float*)d_out;                   // [M, O] fp32

  const int O = in_sizes[3];       // 4096
  const int K = in_sizes[1] / O;   // 4096
  const int NB = in_sizes[2] / O;  // 128
  const int M = in_sizes[0] / K;   // 4096
  (void)n_in; (void)out_size;

  const size_t Wbytes = (size_t)O * K * sizeof(bf16_t);  // 32 MiB
  const size_t Xbytes = (size_t)M * K * sizeof(bf16_t);  // 32 MiB
  dim3 grid(O / 128, M / 128);  // (n-tiles, m-tiles)

  if (ws_size >= Wbytes + Xbytes) {
    bf16_t* W = (bf16_t*)d_ws;
    bf16_t* Xb = (bf16_t*)((char*)d_ws + Wbytes);
    dequant_kernel<<<(int)((size_t)O * K / 2048), 256, 0, stream>>>(qw, scales,
                                                                    W, K, NB);
    cvt_kernel<<<(int)((size_t)M * K / 2048), 256, 0, stream>>>(x, Xb);
    gemm_bt<0><<<grid, 256, 0, stream>>>(Xb, nullptr, W, nullptr, nullptr,
                                         bias, out, M, O, K, NB);
  } else if (ws_size >= Wbytes) {
    bf16_t* W = (bf16_t*)d_ws;
    dequant_kernel<<<(int)((size_t)O * K / 2048), 256, 0, stream>>>(qw, scales,
                                                                    W, K, NB);
    gemm_bt<1><<<grid, 256, 0, stream>>>(nullptr, x, W, nullptr, nullptr, bias,
                                         out, M, O, K, NB);
  } else {
    gemm_bt<2><<<grid, 256, 0, stream>>>(nullptr, x, nullptr, qw, scales, bias,
                                         out, M, O, K, NB);
  }
}

// Round 4
// 370.956 us; speedup vs baseline: 1.0674x; 1.0674x over previous
//
#include <hip/hip_runtime.h>
#include <stdint.h>

// Q8_0-style dequant + linear. Harness upcasts f16 -> fp32: x/scales/bias are
// const float*, out is float*. q_weight is int32.
//   W[o,k] = (q[o,k]-128) * scales[o,k/32]
//   out[m,o] = sum_k x[m,k]*W[o,k] + bias[o]   (bf16 MFMA, fp32 accum/out)
// M = 4096, N = O = 4096, K = 4096.
//
// R4: m97-structure GEMM — global_load_lds width=16 async staging (the
// verified 517->874 TF ladder step). Aux passes unchanged from R3 (PASS).

#define QOFF 128

typedef __bf16 bf16_t;
typedef __bf16 bf16x8 __attribute__((ext_vector_type(8)));
typedef float f32x4 __attribute__((ext_vector_type(4)));

// ---------------------------------------------------------------------------
// Pass 1a: x fp32 -> bf16.
// ---------------------------------------------------------------------------
__global__ __launch_bounds__(256) void cvt_kernel(const float* __restrict__ X,
                                                  bf16_t* __restrict__ Xb) {
  const size_t e = ((size_t)blockIdx.x * 256 + threadIdx.x) * 8;
  float4 a = *(const float4*)(X + e);
  float4 b = *(const float4*)(X + e + 4);
  bf16x8 t;
  t[0] = (bf16_t)a.x; t[1] = (bf16_t)a.y; t[2] = (bf16_t)a.z; t[3] = (bf16_t)a.w;
  t[4] = (bf16_t)b.x; t[5] = (bf16_t)b.y; t[6] = (bf16_t)b.z; t[7] = (bf16_t)b.w;
  *(bf16x8*)(Xb + e) = t;
}

// ---------------------------------------------------------------------------
// Pass 1b: dequant q (int32 [O,K]) + scales (fp32 [O,NB]) -> bf16 W [O,K].
// ---------------------------------------------------------------------------
__global__ __launch_bounds__(256) void dequant_kernel(
    const int* __restrict__ q, const float* __restrict__ scales,
    bf16_t* __restrict__ W, int K, int NB) {
  const size_t e = ((size_t)blockIdx.x * 256 + threadIdx.x) * 8;
  const int o = (int)(e / (size_t)K);
  const int i = (int)(e % (size_t)K);
  const float s = scales[o * NB + (i >> 5)];

  int4 a = *(const int4*)(q + e);
  int4 b = *(const int4*)(q + e + 4);
  const int* av = (const int*)&a;
  const int* bv = (const int*)&b;

  bf16x8 t;
#pragma unroll
  for (int j = 0; j < 4; ++j) t[j] = (bf16_t)((float)(av[j] - QOFF) * s);
#pragma unroll
  for (int j = 0; j < 4; ++j) t[4 + j] = (bf16_t)((float)(bv[j] - QOFF) * s);

  *(bf16x8*)(W + e) = t;
}

// ---------------------------------------------------------------------------
// Pass 2 (main): m97-structure bf16 GEMM, B^T layout, BK=32, 128x128 tile.
// 256 threads = 4 waves (2x2), 64x64/wave = 4x4 frags of 16x16x32.
// Staging via global_load_lds width=16. LDS tiles flat row-major 128x32 (no
// padding): lane l of wave w writes base + w*1024B + l*16B — satisfies the
// wave-uniform-base + lane*size constraint.
// ---------------------------------------------------------------------------
__device__ __forceinline__ void async16(bf16_t* lds, const bf16_t* g) {
  __builtin_amdgcn_global_load_lds(
      (const __attribute__((address_space(1))) unsigned int*)(const void*)g,
      (__attribute__((address_space(3))) unsigned int*)(void*)lds, 16, 0, 0);
}

__global__ __launch_bounds__(256) void gemm_async(
    const bf16_t* __restrict__ A,   // [M, K] x (bf16)
    const bf16_t* __restrict__ B,   // [N, K] dequantized W (bf16)
    const float* __restrict__ bias, // [N]
    float* __restrict__ C,          // [M, N] fp32
    int M, int N, int K) {
  __shared__ bf16_t lsA[128 * 32];
  __shared__ bf16_t lsB[128 * 32];

  const int tid = threadIdx.x;
  const int lane = tid & 63;
  const int wave = tid >> 6;
  const int m0 = blockIdx.y * 128;
  const int n0 = blockIdx.x * 128;
  const int wm = (wave >> 1) * 64;
  const int wn = (wave & 1) * 64;
  const int r = lane & 15;   // fragment m (A) / n (B) index
  const int qd = lane >> 4;  // quad: k-group for inputs, row-group for C/D

  f32x4 acc[4][4] = {};

  // Staging: 128x32 tile = 4096 elems; 256 threads x 8 elems x 2 issues.
  const int e0 = tid * 8;
  const int e1 = 2048 + tid * 8;
  const int r0 = e0 >> 5, c0 = e0 & 31;
  const int r1 = e1 >> 5, c1 = e1 & 31;

  const bf16_t* gA0 = A + (size_t)(m0 + r0) * K + c0;
  const bf16_t* gA1 = A + (size_t)(m0 + r1) * K + c1;
  const bf16_t* gB0 = B + (size_t)(n0 + r0) * K + c0;
  const bf16_t* gB1 = B + (size_t)(n0 + r1) * K + c1;

  for (int k0 = 0; k0 < K; k0 += 32) {
    async16(&lsA[e0], gA0 + k0);
    async16(&lsA[e1], gA1 + k0);
    async16(&lsB[e0], gB0 + k0);
    async16(&lsB[e1], gB1 + k0);
    __syncthreads();  // drains vmcnt: staged tile visible to all waves

    bf16x8 af[4], bfv[4];
#pragma unroll
    for (int i = 0; i < 4; ++i) {
      af[i] = *(const bf16x8*)&lsA[(wm + i * 16 + r) * 32 + qd * 8];
      bfv[i] = *(const bf16x8*)&lsB[(wn + i * 16 + r) * 32 + qd * 8];
    }
#pragma unroll
    for (int mi = 0; mi < 4; ++mi)
#pragma unroll
      for (int ni = 0; ni < 4; ++ni)
        acc[mi][ni] = __builtin_amdgcn_mfma_f32_16x16x32_bf16(
            af[mi], bfv[ni], acc[mi][ni], 0, 0, 0);
    __syncthreads();  // all waves done reading before next stage overwrites
  }

  // Epilogue: C/D mapping col = lane&15 (n), row = qd*4 + reg (m). fp32 out.
#pragma unroll
  for (int ni = 0; ni < 4; ++ni) {
    const int n = n0 + wn + ni * 16 + r;
    const float bv = bias[n];
#pragma unroll
    for (int mi = 0; mi < 4; ++mi) {
      const int mbase = m0 + wm + mi * 16 + qd * 4;
#pragma unroll
      for (int reg = 0; reg < 4; ++reg) {
        C[(size_t)(mbase + reg) * N + n] = acc[mi][ni][reg] + bv;
      }
    }
  }
}

// ---------------------------------------------------------------------------
// Fallback (small ws): register-staged GEMM, fused A-convert + B-dequant.
// ---------------------------------------------------------------------------
__global__ __launch_bounds__(256) void gemm_fused(
    const float* __restrict__ Af, const int* __restrict__ q,
    const float* __restrict__ scales, const float* __restrict__ bias,
    float* __restrict__ C, int M, int N, int K, int NB) {
  __shared__ bf16_t lsA[128 * 32];
  __shared__ bf16_t lsB[128 * 32];

  const int tid = threadIdx.x;
  const int lane = tid & 63;
  const int wave = tid >> 6;
  const int m0 = blockIdx.y * 128;
  const int n0 = blockIdx.x * 128;
  const int wm = (wave >> 1) * 64;
  const int wn = (wave & 1) * 64;
  const int r = lane & 15;
  const int qd = lane >> 4;

  const int e = tid * 16;
  const int row = e >> 5;
  const int col = e & 31;

  const float* gAf = Af + (size_t)(m0 + row) * K + col;
  const int* gQ = q + (size_t)(n0 + row) * K + col;
  const float* gS = scales + (size_t)(n0 + row) * NB;

  f32x4 acc[4][4] = {};

  for (int k0 = 0; k0 < K; k0 += 32) {
    bf16x8 a0, a1, b0, b1;
    {
      float4 f0 = *(const float4*)(gAf + k0);
      float4 f1 = *(const float4*)(gAf + k0 + 4);
      float4 f2 = *(const float4*)(gAf + k0 + 8);
      float4 f3 = *(const float4*)(gAf + k0 + 12);
      a0[0] = (bf16_t)f0.x; a0[1] = (bf16_t)f0.y; a0[2] = (bf16_t)f0.z; a0[3] = (bf16_t)f0.w;
      a0[4] = (bf16_t)f1.x; a0[5] = (bf16_t)f1.y; a0[6] = (bf16_t)f1.z; a0[7] = (bf16_t)f1.w;
      a1[0] = (bf16_t)f2.x; a1[1] = (bf16_t)f2.y; a1[2] = (bf16_t)f2.z; a1[3] = (bf16_t)f2.w;
      a1[4] = (bf16_t)f3.x; a1[5] = (bf16_t)f3.y; a1[6] = (bf16_t)f3.z; a1[7] = (bf16_t)f3.w;
    }
    {
      const float s = gS[k0 >> 5];
      int qv[16];
      *(int4*)&qv[0] = *(const int4*)(gQ + k0);
      *(int4*)&qv[4] = *(const int4*)(gQ + k0 + 4);
      *(int4*)&qv[8] = *(const int4*)(gQ + k0 + 8);
      *(int4*)&qv[12] = *(const int4*)(gQ + k0 + 12);
#pragma unroll
      for (int j = 0; j < 8; ++j) b0[j] = (bf16_t)((float)(qv[j] - QOFF) * s);
#pragma unroll
      for (int j = 0; j < 8; ++j)
        b1[j] = (bf16_t)((float)(qv[8 + j] - QOFF) * s);
    }

    __syncthreads();
    *(bf16x8*)&lsA[e] = a0;
    *(bf16x8*)&lsA[e + 8] = a1;
    *(bf16x8*)&lsB[e] = b0;
    *(bf16x8*)&lsB[e + 8] = b1;
    __syncthreads();

    bf16x8 af[4], bfv[4];
#pragma unroll
    for (int i = 0; i < 4; ++i) {
      af[i] = *(const bf16x8*)&lsA[(wm + i * 16 + r) * 32 + qd * 8];
      bfv[i] = *(const bf16x8*)&lsB[(wn + i * 16 + r) * 32 + qd * 8];
    }
#pragma unroll
    for (int mi = 0; mi < 4; ++mi)
#pragma unroll
      for (int ni = 0; ni < 4; ++ni)
        acc[mi][ni] = __builtin_amdgcn_mfma_f32_16x16x32_bf16(
            af[mi], bfv[ni], acc[mi][ni], 0, 0, 0);
  }

#pragma unroll
  for (int ni = 0; ni < 4; ++ni) {
    const int n = n0 + wn + ni * 16 + r;
    const float bv = bias[n];
#pragma unroll
    for (int mi = 0; mi < 4; ++mi) {
      const int mbase = m0 + wm + mi * 16 + qd * 4;
#pragma unroll
      for (int reg = 0; reg < 4; ++reg) {
        C[(size_t)(mbase + reg) * N + n] = acc[mi][ni][reg] + bv;
      }
    }
  }
}

// ---------------------------------------------------------------------------
extern "C" void kernel_launch(void* const* d_in, const int* in_sizes, int n_in,
                              void* d_out, int out_size, void* d_ws,
                              size_t ws_size, hipStream_t stream) {
  const float* x = (const float*)d_in[0];       // [M, K] fp32 (f16 upcast)
  const int* qw = (const int*)d_in[1];          // [O, K] int32
  const float* scales = (const float*)d_in[2];  // [O, NB] fp32
  const float* bias = (const float*)d_in[3];    // [O] fp32
  float* out = (float*)d_out;                   // [M, O] fp32

  const int O = in_sizes[3];       // 4096
  const int K = in_sizes[1] / O;   // 4096
  const int NB = in_sizes[2] / O;  // 128
  const int M = in_sizes[0] / K;   // 4096
  (void)n_in; (void)out_size;

  const size_t Wbytes = (size_t)O * K * sizeof(bf16_t);  // 32 MiB
  const size_t Xbytes = (size_t)M * K * sizeof(bf16_t);  // 32 MiB
  dim3 grid(O / 128, M / 128);

  if (ws_size >= Wbytes + Xbytes) {
    bf16_t* W = (bf16_t*)d_ws;
    bf16_t* Xb = (bf16_t*)((char*)d_ws + Wbytes);
    dequant_kernel<<<(int)((size_t)O * K / 2048), 256, 0, stream>>>(qw, scales,
                                                                    W, K, NB);
    cvt_kernel<<<(int)((size_t)M * K / 2048), 256, 0, stream>>>(x, Xb);
    gemm_async<<<grid, 256, 0, stream>>>(Xb, W, bias, out, M, O, K);
  } else {
    gemm_fused<<<grid, 256, 0, stream>>>(x, qw, scales, bias, out, M, O, K,
                                         NB);
  }
}

// Round 5
// 355.760 us; speedup vs baseline: 1.1130x; 1.0427x over previous
//
#include <hip/hip_runtime.h>
#include <stdint.h>

// Q8_0-style dequant + linear. Harness upcasts f16 -> fp32: x/scales/bias are
// const float*, out is float*. q_weight is int32.
//   W[o,k] = (q[o,k]-128) * scales[o,k/32]
//   out[m,o] = sum_k x[m,k]*W[o,k] + bias[o]   (bf16 MFMA, fp32 accum/out)
// M = 4096, N = O = 4096, K = 4096.
//
// R5: (1) single-barrier double-buffered K-loop — prefetch tile k+1 via
// global_load_lds right after the barrier, MFMA on tile k overlaps the DMA.
// (2) dequant + x-convert fused into one prep launch.

#define QOFF 128

typedef __bf16 bf16_t;
typedef __bf16 bf16x8 __attribute__((ext_vector_type(8)));
typedef float f32x4 __attribute__((ext_vector_type(4)));

// ---------------------------------------------------------------------------
// Prep: blocks [0, nDeq) dequant q->W (bf16); blocks [nDeq, nDeq+nCvt) convert
// x fp32->bf16. Both 8 elems/thread, fully coalesced.
// ---------------------------------------------------------------------------
__global__ __launch_bounds__(256) void prep_kernel(
    const int* __restrict__ q, const float* __restrict__ scales,
    const float* __restrict__ X, bf16_t* __restrict__ W,
    bf16_t* __restrict__ Xb, int K, int NB, int nDeq) {
  const int b = blockIdx.x;
  if (b < nDeq) {
    const size_t e = ((size_t)b * 256 + threadIdx.x) * 8;
    const int o = (int)(e / (size_t)K);
    const int i = (int)(e % (size_t)K);
    const float s = scales[o * NB + (i >> 5)];
    int4 a = *(const int4*)(q + e);
    int4 c = *(const int4*)(q + e + 4);
    const int* av = (const int*)&a;
    const int* cv = (const int*)&c;
    bf16x8 t;
#pragma unroll
    for (int j = 0; j < 4; ++j) t[j] = (bf16_t)((float)(av[j] - QOFF) * s);
#pragma unroll
    for (int j = 0; j < 4; ++j) t[4 + j] = (bf16_t)((float)(cv[j] - QOFF) * s);
    *(bf16x8*)(W + e) = t;
  } else {
    const size_t e = ((size_t)(b - nDeq) * 256 + threadIdx.x) * 8;
    float4 a = *(const float4*)(X + e);
    float4 c = *(const float4*)(X + e + 4);
    bf16x8 t;
    t[0] = (bf16_t)a.x; t[1] = (bf16_t)a.y; t[2] = (bf16_t)a.z; t[3] = (bf16_t)a.w;
    t[4] = (bf16_t)c.x; t[5] = (bf16_t)c.y; t[6] = (bf16_t)c.z; t[7] = (bf16_t)c.w;
    *(bf16x8*)(Xb + e) = t;
  }
}

// ---------------------------------------------------------------------------
// GEMM: 128x128 tile, BK=32, B^T layout, 4 waves (2x2), 64x64/wave = 4x4
// frags of mfma_f32_16x16x32_bf16. Double-buffered LDS, ONE barrier per
// K-iter: barrier publishes buf[cur] (vmcnt drain) and separates last iter's
// reads of buf[nxt] from this iter's prefetch writes into buf[nxt].
// LDS dst = wave-uniform base + lane*16 (flat row-major, no padding).
// ---------------------------------------------------------------------------
__device__ __forceinline__ void async16(bf16_t* lds, const bf16_t* g) {
  __builtin_amdgcn_global_load_lds(
      (const __attribute__((address_space(1))) unsigned int*)(const void*)g,
      (__attribute__((address_space(3))) unsigned int*)(void*)lds, 16, 0, 0);
}

__global__ __launch_bounds__(256) void gemm_db(
    const bf16_t* __restrict__ A,   // [M, K] x (bf16)
    const bf16_t* __restrict__ B,   // [N, K] dequantized W (bf16)
    const float* __restrict__ bias, // [N]
    float* __restrict__ C,          // [M, N] fp32
    int M, int N, int K) {
  __shared__ bf16_t lsA[2][128 * 32];
  __shared__ bf16_t lsB[2][128 * 32];

  const int tid = threadIdx.x;
  const int lane = tid & 63;
  const int wave = tid >> 6;
  const int m0 = blockIdx.y * 128;
  const int n0 = blockIdx.x * 128;
  const int wm = (wave >> 1) * 64;
  const int wn = (wave & 1) * 64;
  const int r = lane & 15;   // fragment m (A) / n (B) index
  const int qd = lane >> 4;  // quad: k-group for inputs, row-group for C/D

  f32x4 acc[4][4] = {};

  // Staging: 128x32 tile = 4096 elems; 256 threads x 8 elems x 2 issues.
  const int e0 = tid * 8;
  const int e1 = 2048 + tid * 8;
  const int r0 = e0 >> 5, c0 = e0 & 31;
  const int r1 = e1 >> 5, c1 = e1 & 31;

  const bf16_t* gA0 = A + (size_t)(m0 + r0) * K + c0;
  const bf16_t* gA1 = A + (size_t)(m0 + r1) * K + c1;
  const bf16_t* gB0 = B + (size_t)(n0 + r0) * K + c0;
  const bf16_t* gB1 = B + (size_t)(n0 + r1) * K + c1;

  // Prefetch tile 0 into buf 0.
  async16(&lsA[0][e0], gA0);
  async16(&lsA[0][e1], gA1);
  async16(&lsB[0][e0], gB0);
  async16(&lsB[0][e1], gB1);

  int buf = 0;
  for (int k0 = 0; k0 < K; k0 += 32, buf ^= 1) {
    __syncthreads();  // vmcnt drain -> buf[buf] ready; prior reads of buf^1 done
    if (k0 + 32 < K) {
      const int nk = k0 + 32;
      async16(&lsA[buf ^ 1][e0], gA0 + nk);
      async16(&lsA[buf ^ 1][e1], gA1 + nk);
      async16(&lsB[buf ^ 1][e0], gB0 + nk);
      async16(&lsB[buf ^ 1][e1], gB1 + nk);
    }

    bf16x8 af[4], bfv[4];
#pragma unroll
    for (int i = 0; i < 4; ++i) {
      af[i] = *(const bf16x8*)&lsA[buf][(wm + i * 16 + r) * 32 + qd * 8];
      bfv[i] = *(const bf16x8*)&lsB[buf][(wn + i * 16 + r) * 32 + qd * 8];
    }
#pragma unroll
    for (int mi = 0; mi < 4; ++mi)
#pragma unroll
      for (int ni = 0; ni < 4; ++ni)
        acc[mi][ni] = __builtin_amdgcn_mfma_f32_16x16x32_bf16(
            af[mi], bfv[ni], acc[mi][ni], 0, 0, 0);
  }

  // Epilogue: C/D mapping col = lane&15 (n), row = qd*4 + reg (m). fp32 out.
#pragma unroll
  for (int ni = 0; ni < 4; ++ni) {
    const int n = n0 + wn + ni * 16 + r;
    const float bv = bias[n];
#pragma unroll
    for (int mi = 0; mi < 4; ++mi) {
      const int mbase = m0 + wm + mi * 16 + qd * 4;
#pragma unroll
      for (int reg = 0; reg < 4; ++reg) {
        C[(size_t)(mbase + reg) * N + n] = acc[mi][ni][reg] + bv;
      }
    }
  }
}

// ---------------------------------------------------------------------------
// Fallback (small ws): register-staged GEMM, fused A-convert + B-dequant.
// ---------------------------------------------------------------------------
__global__ __launch_bounds__(256) void gemm_fused(
    const float* __restrict__ Af, const int* __restrict__ q,
    const float* __restrict__ scales, const float* __restrict__ bias,
    float* __restrict__ C, int M, int N, int K, int NB) {
  __shared__ bf16_t lsA[128 * 32];
  __shared__ bf16_t lsB[128 * 32];

  const int tid = threadIdx.x;
  const int lane = tid & 63;
  const int wave = tid >> 6;
  const int m0 = blockIdx.y * 128;
  const int n0 = blockIdx.x * 128;
  const int wm = (wave >> 1) * 64;
  const int wn = (wave & 1) * 64;
  const int r = lane & 15;
  const int qd = lane >> 4;

  const int e = tid * 16;
  const int row = e >> 5;
  const int col = e & 31;

  const float* gAf = Af + (size_t)(m0 + row) * K + col;
  const int* gQ = q + (size_t)(n0 + row) * K + col;
  const float* gS = scales + (size_t)(n0 + row) * NB;

  f32x4 acc[4][4] = {};

  for (int k0 = 0; k0 < K; k0 += 32) {
    bf16x8 a0, a1, b0, b1;
    {
      float4 f0 = *(const float4*)(gAf + k0);
      float4 f1 = *(const float4*)(gAf + k0 + 4);
      float4 f2 = *(const float4*)(gAf + k0 + 8);
      float4 f3 = *(const float4*)(gAf + k0 + 12);
      a0[0] = (bf16_t)f0.x; a0[1] = (bf16_t)f0.y; a0[2] = (bf16_t)f0.z; a0[3] = (bf16_t)f0.w;
      a0[4] = (bf16_t)f1.x; a0[5] = (bf16_t)f1.y; a0[6] = (bf16_t)f1.z; a0[7] = (bf16_t)f1.w;
      a1[0] = (bf16_t)f2.x; a1[1] = (bf16_t)f2.y; a1[2] = (bf16_t)f2.z; a1[3] = (bf16_t)f2.w;
      a1[4] = (bf16_t)f3.x; a1[5] = (bf16_t)f3.y; a1[6] = (bf16_t)f3.z; a1[7] = (bf16_t)f3.w;
    }
    {
      const float s = gS[k0 >> 5];
      int qv[16];
      *(int4*)&qv[0] = *(const int4*)(gQ + k0);
      *(int4*)&qv[4] = *(const int4*)(gQ + k0 + 4);
      *(int4*)&qv[8] = *(const int4*)(gQ + k0 + 8);
      *(int4*)&qv[12] = *(const int4*)(gQ + k0 + 12);
#pragma unroll
      for (int j = 0; j < 8; ++j) b0[j] = (bf16_t)((float)(qv[j] - QOFF) * s);
#pragma unroll
      for (int j = 0; j < 8; ++j)
        b1[j] = (bf16_t)((float)(qv[8 + j] - QOFF) * s);
    }

    __syncthreads();
    *(bf16x8*)&lsA[e] = a0;
    *(bf16x8*)&lsA[e + 8] = a1;
    *(bf16x8*)&lsB[e] = b0;
    *(bf16x8*)&lsB[e + 8] = b1;
    __syncthreads();

    bf16x8 af[4], bfv[4];
#pragma unroll
    for (int i = 0; i < 4; ++i) {
      af[i] = *(const bf16x8*)&lsA[(wm + i * 16 + r) * 32 + qd * 8];
      bfv[i] = *(const bf16x8*)&lsB[(wn + i * 16 + r) * 32 + qd * 8];
    }
#pragma unroll
    for (int mi = 0; mi < 4; ++mi)
#pragma unroll
      for (int ni = 0; ni < 4; ++ni)
        acc[mi][ni] = __builtin_amdgcn_mfma_f32_16x16x32_bf16(
            af[mi], bfv[ni], acc[mi][ni], 0, 0, 0);
  }

#pragma unroll
  for (int ni = 0; ni < 4; ++ni) {
    const int n = n0 + wn + ni * 16 + r;
    const float bv = bias[n];
#pragma unroll
    for (int mi = 0; mi < 4; ++mi) {
      const int mbase = m0 + wm + mi * 16 + qd * 4;
#pragma unroll
      for (int reg = 0; reg < 4; ++reg) {
        C[(size_t)(mbase + reg) * N + n] = acc[mi][ni][reg] + bv;
      }
    }
  }
}

// ---------------------------------------------------------------------------
extern "C" void kernel_launch(void* const* d_in, const int* in_sizes, int n_in,
                              void* d_out, int out_size, void* d_ws,
                              size_t ws_size, hipStream_t stream) {
  const float* x = (const float*)d_in[0];       // [M, K] fp32 (f16 upcast)
  const int* qw = (const int*)d_in[1];          // [O, K] int32
  const float* scales = (const float*)d_in[2];  // [O, NB] fp32
  const float* bias = (const float*)d_in[3];    // [O] fp32
  float* out = (float*)d_out;                   // [M, O] fp32

  const int O = in_sizes[3];       // 4096
  const int K = in_sizes[1] / O;   // 4096
  const int NB = in_sizes[2] / O;  // 128
  const int M = in_sizes[0] / K;   // 4096
  (void)n_in; (void)out_size;

  const size_t Wbytes = (size_t)O * K * sizeof(bf16_t);  // 32 MiB
  const size_t Xbytes = (size_t)M * K * sizeof(bf16_t);  // 32 MiB
  dim3 grid(O / 128, M / 128);

  if (ws_size >= Wbytes + Xbytes) {
    bf16_t* W = (bf16_t*)d_ws;
    bf16_t* Xb = (bf16_t*)((char*)d_ws + Wbytes);
    const int nDeq = (int)((size_t)O * K / 2048);
    const int nCvt = (int)((size_t)M * K / 2048);
    prep_kernel<<<nDeq + nCvt, 256, 0, stream>>>(qw, scales, x, W, Xb, K, NB,
                                                 nDeq);
    gemm_db<<<grid, 256, 0, stream>>>(Xb, W, bias, out, M, O, K);
  } else {
    gemm_fused<<<grid, 256, 0, stream>>>(x, qw, scales, bias, out, M, O, K,
                                         NB);
  }
}

// Round 6
// 349.053 us; speedup vs baseline: 1.1344x; 1.0192x over previous
//
#include <hip/hip_runtime.h>
#include <stdint.h>

// Q8_0-style dequant + linear. Harness upcasts f16 -> fp32: x/scales/bias are
// const float*, out is float*. q_weight is int32.
//   W[o,k] = (q[o,k]-128) * scales[o,k/32]
//   out[m,o] = sum_k x[m,k]*W[o,k] + bias[o]   (bf16 MFMA, fp32 accum/out)
// M = 4096, N = O = 4096, K = 4096.
//
// R6: 3-stage LDS pipeline, distance-2 global_load_lds prefetch, manual
// s_waitcnt(vmcnt(4), lgkmcnt(0)) + raw s_barrier per iter (m139 pattern) —
// prefetch stays in flight ACROSS the barrier instead of draining.

#define QOFF 128

typedef __bf16 bf16_t;
typedef __bf16 bf16x8 __attribute__((ext_vector_type(8)));
typedef float f32x4 __attribute__((ext_vector_type(4)));

// s_waitcnt simm16 (gfx9/CDNA): [3:0] vmcnt lo, [6:4] expcnt, [11:8] lgkmcnt,
// [15:14] vmcnt hi. expcnt=7 = don't wait. lgkmcnt=0 = wait all LDS ops
// (needed: raw s_barrier has no implicit fence; reads of the buffer we are
// about to DMA-overwrite must be complete before crossing).
#define WAIT_VM4_LGKM0 0x0074  // vmcnt<=4, lgkmcnt=0
#define WAIT_VM0_LGKM0 0x0070  // vmcnt=0,  lgkmcnt=0

// ---------------------------------------------------------------------------
// Prep: blocks [0, nDeq) dequant q->W (bf16); blocks [nDeq, nDeq+nCvt) convert
// x fp32->bf16. 8 elems/thread, coalesced.
// ---------------------------------------------------------------------------
__global__ __launch_bounds__(256) void prep_kernel(
    const int* __restrict__ q, const float* __restrict__ scales,
    const float* __restrict__ X, bf16_t* __restrict__ W,
    bf16_t* __restrict__ Xb, int K, int NB, int nDeq) {
  const int b = blockIdx.x;
  if (b < nDeq) {
    const size_t e = ((size_t)b * 256 + threadIdx.x) * 8;
    const int o = (int)(e / (size_t)K);
    const int i = (int)(e % (size_t)K);
    const float s = scales[o * NB + (i >> 5)];
    int4 a = *(const int4*)(q + e);
    int4 c = *(const int4*)(q + e + 4);
    const int* av = (const int*)&a;
    const int* cv = (const int*)&c;
    bf16x8 t;
#pragma unroll
    for (int j = 0; j < 4; ++j) t[j] = (bf16_t)((float)(av[j] - QOFF) * s);
#pragma unroll
    for (int j = 0; j < 4; ++j) t[4 + j] = (bf16_t)((float)(cv[j] - QOFF) * s);
    *(bf16x8*)(W + e) = t;
  } else {
    const size_t e = ((size_t)(b - nDeq) * 256 + threadIdx.x) * 8;
    float4 a = *(const float4*)(X + e);
    float4 c = *(const float4*)(X + e + 4);
    bf16x8 t;
    t[0] = (bf16_t)a.x; t[1] = (bf16_t)a.y; t[2] = (bf16_t)a.z; t[3] = (bf16_t)a.w;
    t[4] = (bf16_t)c.x; t[5] = (bf16_t)c.y; t[6] = (bf16_t)c.z; t[7] = (bf16_t)c.w;
    *(bf16x8*)(Xb + e) = t;
  }
}

// ---------------------------------------------------------------------------
__device__ __forceinline__ void async16(bf16_t* lds, const bf16_t* g) {
  __builtin_amdgcn_global_load_lds(
      (const __attribute__((address_space(1))) unsigned int*)(const void*)g,
      (__attribute__((address_space(3))) unsigned int*)(void*)lds, 16, 0, 0);
}

// ---------------------------------------------------------------------------
// GEMM: 128x128 tile, BK=32, B^T layout, 4 waves (2x2), 64x64/wave = 4x4
// frags of mfma_f32_16x16x32_bf16. 3-stage LDS pipeline (48 KB), distance-2
// prefetch, manual partial-drain waitcnt + raw barrier.
// Invariant entering iter k: stage k%3 ready, stage (k+1)%3 in flight (4).
// Body: issue stage (k+2)%3 (->8 outstanding); compute k; wait vmcnt(4)
// (stage k+1 landed, k+2 still flying) + lgkmcnt(0); s_barrier.
// Requires (K/32 - 2) % 3 == 0 (K=4096 -> 128 iters = 2 + 3*42).
// ---------------------------------------------------------------------------
__global__ __launch_bounds__(256) void gemm_pipe(
    const bf16_t* __restrict__ A,   // [M, K] x (bf16)
    const bf16_t* __restrict__ B,   // [N, K] dequantized W (bf16)
    const float* __restrict__ bias, // [N]
    float* __restrict__ C,          // [M, N] fp32
    int M, int N, int K) {
  __shared__ bf16_t lsA[3][128 * 32];
  __shared__ bf16_t lsB[3][128 * 32];

  const int tid = threadIdx.x;
  const int lane = tid & 63;
  const int wave = tid >> 6;
  const int m0 = blockIdx.y * 128;
  const int n0 = blockIdx.x * 128;
  const int wm = (wave >> 1) * 64;
  const int wn = (wave & 1) * 64;
  const int r = lane & 15;   // fragment m (A) / n (B) index
  const int qd = lane >> 4;  // quad: k-group for inputs, row-group for C/D

  f32x4 acc[4][4] = {};

  // Staging: 128x32 tile = 4096 elems; 256 threads x 8 elems x 2 issues.
  const int e0 = tid * 8;
  const int e1 = 2048 + tid * 8;
  const int r0 = e0 >> 5, c0 = e0 & 31;
  const int r1 = e1 >> 5, c1 = e1 & 31;

  const bf16_t* gA0 = A + (size_t)(m0 + r0) * K + c0;
  const bf16_t* gA1 = A + (size_t)(m0 + r1) * K + c1;
  const bf16_t* gB0 = B + (size_t)(n0 + r0) * K + c0;
  const bf16_t* gB1 = B + (size_t)(n0 + r1) * K + c1;

  auto issue = [&](int s, int koff) {
    async16(&lsA[s][e0], gA0 + koff);
    async16(&lsA[s][e1], gA1 + koff);
    async16(&lsB[s][e0], gB0 + koff);
    async16(&lsB[s][e1], gB1 + koff);
  };
  auto compute = [&](int s) {
    bf16x8 af[4], bfv[4];
#pragma unroll
    for (int i = 0; i < 4; ++i) {
      af[i] = *(const bf16x8*)&lsA[s][(wm + i * 16 + r) * 32 + qd * 8];
      bfv[i] = *(const bf16x8*)&lsB[s][(wn + i * 16 + r) * 32 + qd * 8];
    }
#pragma unroll
    for (int mi = 0; mi < 4; ++mi)
#pragma unroll
      for (int ni = 0; ni < 4; ++ni)
        acc[mi][ni] = __builtin_amdgcn_mfma_f32_16x16x32_bf16(
            af[mi], bfv[ni], acc[mi][ni], 0, 0, 0);
  };

  const int ITERS = K / 32;  // 128

  issue(0, 0);
  issue(1, 32);
  __builtin_amdgcn_s_waitcnt(WAIT_VM4_LGKM0);  // stage 0 landed
  __builtin_amdgcn_s_barrier();

  int k = 0;
  const int steady = (ITERS - 2) / 3;  // 42
  for (int j = 0; j < steady; ++j) {
#pragma unroll
    for (int u = 0; u < 3; ++u) {
      issue((u + 2) % 3, (k + 2) * 32);  // stage k+2
      compute(u);                        // stage k (== k%3 == u)
      __builtin_amdgcn_s_waitcnt(WAIT_VM4_LGKM0);  // stage k+1 landed
      __builtin_amdgcn_s_barrier();
      ++k;
    }
  }
  // k == ITERS-2 (stage (ITERS-2)%3 == 0 ready, last stage in flight)
  compute(0);
  __builtin_amdgcn_s_waitcnt(WAIT_VM0_LGKM0);  // final stage landed
  __builtin_amdgcn_s_barrier();
  compute(1);

  // Epilogue: C/D mapping col = lane&15 (n), row = qd*4 + reg (m). fp32 out.
#pragma unroll
  for (int ni = 0; ni < 4; ++ni) {
    const int n = n0 + wn + ni * 16 + r;
    const float bv = bias[n];
#pragma unroll
    for (int mi = 0; mi < 4; ++mi) {
      const int mbase = m0 + wm + mi * 16 + qd * 4;
#pragma unroll
      for (int reg = 0; reg < 4; ++reg) {
        C[(size_t)(mbase + reg) * N + n] = acc[mi][ni][reg] + bv;
      }
    }
  }
}

// ---------------------------------------------------------------------------
// Fallback GEMM (any K multiple of 32): R5's double-buffered version.
// ---------------------------------------------------------------------------
__global__ __launch_bounds__(256) void gemm_db(
    const bf16_t* __restrict__ A, const bf16_t* __restrict__ B,
    const float* __restrict__ bias, float* __restrict__ C, int M, int N,
    int K) {
  __shared__ bf16_t lsA[2][128 * 32];
  __shared__ bf16_t lsB[2][128 * 32];

  const int tid = threadIdx.x;
  const int lane = tid & 63;
  const int wave = tid >> 6;
  const int m0 = blockIdx.y * 128;
  const int n0 = blockIdx.x * 128;
  const int wm = (wave >> 1) * 64;
  const int wn = (wave & 1) * 64;
  const int r = lane & 15;
  const int qd = lane >> 4;

  f32x4 acc[4][4] = {};

  const int e0 = tid * 8;
  const int e1 = 2048 + tid * 8;
  const int r0 = e0 >> 5, c0 = e0 & 31;
  const int r1 = e1 >> 5, c1 = e1 & 31;

  const bf16_t* gA0 = A + (size_t)(m0 + r0) * K + c0;
  const bf16_t* gA1 = A + (size_t)(m0 + r1) * K + c1;
  const bf16_t* gB0 = B + (size_t)(n0 + r0) * K + c0;
  const bf16_t* gB1 = B + (size_t)(n0 + r1) * K + c1;

  async16(&lsA[0][e0], gA0);
  async16(&lsA[0][e1], gA1);
  async16(&lsB[0][e0], gB0);
  async16(&lsB[0][e1], gB1);

  int buf = 0;
  for (int k0 = 0; k0 < K; k0 += 32, buf ^= 1) {
    __syncthreads();
    if (k0 + 32 < K) {
      const int nk = k0 + 32;
      async16(&lsA[buf ^ 1][e0], gA0 + nk);
      async16(&lsA[buf ^ 1][e1], gA1 + nk);
      async16(&lsB[buf ^ 1][e0], gB0 + nk);
      async16(&lsB[buf ^ 1][e1], gB1 + nk);
    }
    bf16x8 af[4], bfv[4];
#pragma unroll
    for (int i = 0; i < 4; ++i) {
      af[i] = *(const bf16x8*)&lsA[buf][(wm + i * 16 + r) * 32 + qd * 8];
      bfv[i] = *(const bf16x8*)&lsB[buf][(wn + i * 16 + r) * 32 + qd * 8];
    }
#pragma unroll
    for (int mi = 0; mi < 4; ++mi)
#pragma unroll
      for (int ni = 0; ni < 4; ++ni)
        acc[mi][ni] = __builtin_amdgcn_mfma_f32_16x16x32_bf16(
            af[mi], bfv[ni], acc[mi][ni], 0, 0, 0);
  }

#pragma unroll
  for (int ni = 0; ni < 4; ++ni) {
    const int n = n0 + wn + ni * 16 + r;
    const float bv = bias[n];
#pragma unroll
    for (int mi = 0; mi < 4; ++mi) {
      const int mbase = m0 + wm + mi * 16 + qd * 4;
#pragma unroll
      for (int reg = 0; reg < 4; ++reg) {
        C[(size_t)(mbase + reg) * N + n] = acc[mi][ni][reg] + bv;
      }
    }
  }
}

// ---------------------------------------------------------------------------
// Fallback (small ws): register-staged GEMM, fused A-convert + B-dequant.
// ---------------------------------------------------------------------------
__global__ __launch_bounds__(256) void gemm_fused(
    const float* __restrict__ Af, const int* __restrict__ q,
    const float* __restrict__ scales, const float* __restrict__ bias,
    float* __restrict__ C, int M, int N, int K, int NB) {
  __shared__ bf16_t lsA[128 * 32];
  __shared__ bf16_t lsB[128 * 32];

  const int tid = threadIdx.x;
  const int lane = tid & 63;
  const int wave = tid >> 6;
  const int m0 = blockIdx.y * 128;
  const int n0 = blockIdx.x * 128;
  const int wm = (wave >> 1) * 64;
  const int wn = (wave & 1) * 64;
  const int r = lane & 15;
  const int qd = lane >> 4;

  const int e = tid * 16;
  const int row = e >> 5;
  const int col = e & 31;

  const float* gAf = Af + (size_t)(m0 + row) * K + col;
  const int* gQ = q + (size_t)(n0 + row) * K + col;
  const float* gS = scales + (size_t)(n0 + row) * NB;

  f32x4 acc[4][4] = {};

  for (int k0 = 0; k0 < K; k0 += 32) {
    bf16x8 a0, a1, b0, b1;
    {
      float4 f0 = *(const float4*)(gAf + k0);
      float4 f1 = *(const float4*)(gAf + k0 + 4);
      float4 f2 = *(const float4*)(gAf + k0 + 8);
      float4 f3 = *(const float4*)(gAf + k0 + 12);
      a0[0] = (bf16_t)f0.x; a0[1] = (bf16_t)f0.y; a0[2] = (bf16_t)f0.z; a0[3] = (bf16_t)f0.w;
      a0[4] = (bf16_t)f1.x; a0[5] = (bf16_t)f1.y; a0[6] = (bf16_t)f1.z; a0[7] = (bf16_t)f1.w;
      a1[0] = (bf16_t)f2.x; a1[1] = (bf16_t)f2.y; a1[2] = (bf16_t)f2.z; a1[3] = (bf16_t)f2.w;
      a1[4] = (bf16_t)f3.x; a1[5] = (bf16_t)f3.y; a1[6] = (bf16_t)f3.z; a1[7] = (bf16_t)f3.w;
    }
    {
      const float s = gS[k0 >> 5];
      int qv[16];
      *(int4*)&qv[0] = *(const int4*)(gQ + k0);
      *(int4*)&qv[4] = *(const int4*)(gQ + k0 + 4);
      *(int4*)&qv[8] = *(const int4*)(gQ + k0 + 8);
      *(int4*)&qv[12] = *(const int4*)(gQ + k0 + 12);
#pragma unroll
      for (int j = 0; j < 8; ++j) b0[j] = (bf16_t)((float)(qv[j] - QOFF) * s);
#pragma unroll
      for (int j = 0; j < 8; ++j)
        b1[j] = (bf16_t)((float)(qv[8 + j] - QOFF) * s);
    }

    __syncthreads();
    *(bf16x8*)&lsA[e] = a0;
    *(bf16x8*)&lsA[e + 8] = a1;
    *(bf16x8*)&lsB[e] = b0;
    *(bf16x8*)&lsB[e + 8] = b1;
    __syncthreads();

    bf16x8 af[4], bfv[4];
#pragma unroll
    for (int i = 0; i < 4; ++i) {
      af[i] = *(const bf16x8*)&lsA[(wm + i * 16 + r) * 32 + qd * 8];
      bfv[i] = *(const bf16x8*)&lsB[(wn + i * 16 + r) * 32 + qd * 8];
    }
#pragma unroll
    for (int mi = 0; mi < 4; ++mi)
#pragma unroll
      for (int ni = 0; ni < 4; ++ni)
        acc[mi][ni] = __builtin_amdgcn_mfma_f32_16x16x32_bf16(
            af[mi], bfv[ni], acc[mi][ni], 0, 0, 0);
  }

#pragma unroll
  for (int ni = 0; ni < 4; ++ni) {
    const int n = n0 + wn + ni * 16 + r;
    const float bv = bias[n];
#pragma unroll
    for (int mi = 0; mi < 4; ++mi) {
      const int mbase = m0 + wm + mi * 16 + qd * 4;
#pragma unroll
      for (int reg = 0; reg < 4; ++reg) {
        C[(size_t)(mbase + reg) * N + n] = acc[mi][ni][reg] + bv;
      }
    }
  }
}

// ---------------------------------------------------------------------------
extern "C" void kernel_launch(void* const* d_in, const int* in_sizes, int n_in,
                              void* d_out, int out_size, void* d_ws,
                              size_t ws_size, hipStream_t stream) {
  const float* x = (const float*)d_in[0];       // [M, K] fp32 (f16 upcast)
  const int* qw = (const int*)d_in[1];          // [O, K] int32
  const float* scales = (const float*)d_in[2];  // [O, NB] fp32
  const float* bias = (const float*)d_in[3];    // [O] fp32
  float* out = (float*)d_out;                   // [M, O] fp32

  const int O = in_sizes[3];       // 4096
  const int K = in_sizes[1] / O;   // 4096
  const int NB = in_sizes[2] / O;  // 128
  const int M = in_sizes[0] / K;   // 4096
  (void)n_in; (void)out_size;

  const size_t Wbytes = (size_t)O * K * sizeof(bf16_t);  // 32 MiB
  const size_t Xbytes = (size_t)M * K * sizeof(bf16_t);  // 32 MiB
  dim3 grid(O / 128, M / 128);

  if (ws_size >= Wbytes + Xbytes) {
    bf16_t* W = (bf16_t*)d_ws;
    bf16_t* Xb = (bf16_t*)((char*)d_ws + Wbytes);
    const int nDeq = (int)((size_t)O * K / 2048);
    const int nCvt = (int)((size_t)M * K / 2048);
    prep_kernel<<<nDeq + nCvt, 256, 0, stream>>>(qw, scales, x, W, Xb, K, NB,
                                                 nDeq);
    const int iters = K / 32;
    if (iters >= 5 && (iters - 2) % 3 == 0) {
      gemm_pipe<<<grid, 256, 0, stream>>>(Xb, W, bias, out, M, O, K);
    } else {
      gemm_db<<<grid, 256, 0, stream>>>(Xb, W, bias, out, M, O, K);
    }
  } else {
    gemm_fused<<<grid, 256, 0, stream>>>(x, qw, scales, bias, out, M, O, K,
                                         NB);
  }
}

// Round 7
// 305.867 us; speedup vs baseline: 1.2945x; 1.1412x over previous
//
#include <hip/hip_runtime.h>
#include <stdint.h>

// Q8_0-style dequant + linear. Harness upcasts f16 -> fp32: x/scales/bias are
// const float*, out is float*. q_weight is int32.
//   W[o,k] = (q[o,k]-128) * scales[o,k/32]
//   out[m,o] = sum_k x[m,k]*W[o,k] + bias[o]   (bf16 MFMA, fp32 accum/out)
// M = 4096, N = O = 4096, K = 4096.
//
// R7: block tile 128x256, 4 waves of 64x128 (4x8 frags) — raises FLOP per
// LDS-byte from 32 to 43.7, attacking the measured LDS-read-bandwidth wall
// (R6 model: LDS port ~75% busy vs MFMA 30%). 3-stage distance-2 pipeline
// with partial-drain waitcnt retained (6 DMA issues/stage -> vmcnt(6)).

#define QOFF 128

typedef __bf16 bf16_t;
typedef __bf16 bf16x8 __attribute__((ext_vector_type(8)));
typedef float f32x4 __attribute__((ext_vector_type(4)));

// s_waitcnt simm16: [3:0] vmcnt lo, [6:4] expcnt(=7 none), [11:8] lgkmcnt,
// [15:14] vmcnt hi. lgkmcnt=0: raw s_barrier has no implicit fence — LDS
// reads of the stage about to be DMA-overwritten must complete first.
#define WAIT_VM6_LGKM0 0x0076  // vmcnt<=6 (stage k+2 stays in flight)
#define WAIT_VM0_LGKM0 0x0070  // vmcnt=0

// ---------------------------------------------------------------------------
// Prep: blocks [0, nDeq) dequant q->W (bf16); rest convert x fp32->bf16.
// ---------------------------------------------------------------------------
__global__ __launch_bounds__(256) void prep_kernel(
    const int* __restrict__ q, const float* __restrict__ scales,
    const float* __restrict__ X, bf16_t* __restrict__ W,
    bf16_t* __restrict__ Xb, int K, int NB, int nDeq) {
  const int b = blockIdx.x;
  if (b < nDeq) {
    const size_t e = ((size_t)b * 256 + threadIdx.x) * 8;
    const int o = (int)(e / (size_t)K);
    const int i = (int)(e % (size_t)K);
    const float s = scales[o * NB + (i >> 5)];
    int4 a = *(const int4*)(q + e);
    int4 c = *(const int4*)(q + e + 4);
    const int* av = (const int*)&a;
    const int* cv = (const int*)&c;
    bf16x8 t;
#pragma unroll
    for (int j = 0; j < 4; ++j) t[j] = (bf16_t)((float)(av[j] - QOFF) * s);
#pragma unroll
    for (int j = 0; j < 4; ++j) t[4 + j] = (bf16_t)((float)(cv[j] - QOFF) * s);
    *(bf16x8*)(W + e) = t;
  } else {
    const size_t e = ((size_t)(b - nDeq) * 256 + threadIdx.x) * 8;
    float4 a = *(const float4*)(X + e);
    float4 c = *(const float4*)(X + e + 4);
    bf16x8 t;
    t[0] = (bf16_t)a.x; t[1] = (bf16_t)a.y; t[2] = (bf16_t)a.z; t[3] = (bf16_t)a.w;
    t[4] = (bf16_t)c.x; t[5] = (bf16_t)c.y; t[6] = (bf16_t)c.z; t[7] = (bf16_t)c.w;
    *(bf16x8*)(Xb + e) = t;
  }
}

// ---------------------------------------------------------------------------
__device__ __forceinline__ void async16(bf16_t* lds, const bf16_t* g) {
  __builtin_amdgcn_global_load_lds(
      (const __attribute__((address_space(1))) unsigned int*)(const void*)g,
      (__attribute__((address_space(3))) unsigned int*)(void*)lds, 16, 0, 0);
}

// ---------------------------------------------------------------------------
// Main GEMM: 128(M)x256(N) block, BK=32, 4 waves as 2x2 of 64x128 wave-tiles
// (4x8 frags of mfma_f32_16x16x32_bf16, acc = 128 VGPR). 3-stage LDS
// pipeline (72 KB), distance-2 prefetch, partial-drain waitcnt + raw barrier.
// Per iter: 6 DMA issues (A: 2, B: 4). Steady wait vmcnt(6) retires stage
// k+1, leaves k+2 flying across the barrier.
// Requires (K/32 - 2) % 3 == 0, M%128==0, N%256==0.
// ---------------------------------------------------------------------------
__global__ __launch_bounds__(256, 2) void gemm_pipe2(
    const bf16_t* __restrict__ A,   // [M, K] x (bf16)
    const bf16_t* __restrict__ B,   // [N, K] dequantized W (bf16)
    const float* __restrict__ bias, // [N]
    float* __restrict__ C,          // [M, N] fp32
    int M, int N, int K) {
  __shared__ bf16_t lsA[3][128 * 32];  // 8 KB / stage
  __shared__ bf16_t lsB[3][256 * 32];  // 16 KB / stage

  const int tid = threadIdx.x;
  const int lane = tid & 63;
  const int wave = tid >> 6;
  const int m0 = blockIdx.y * 128;
  const int n0 = blockIdx.x * 256;
  const int wm = (wave >> 1) * 64;   // wave-tile m origin
  const int wn = (wave & 1) * 128;   // wave-tile n origin
  const int r = lane & 15;           // fragment m (A) / n (B) index
  const int qd = lane >> 4;          // quad: k-group (in), row-group (C/D)

  f32x4 acc[4][8] = {};

  // Staging. A-tile 128x32 = 4096 elems: 2 issues. B-tile 256x32 = 8192: 4.
  const int ea0 = tid * 8;
  const int ea1 = 2048 + tid * 8;
  const bf16_t* gA0 = A + (size_t)(m0 + (ea0 >> 5)) * K + (ea0 & 31);
  const bf16_t* gA1 = A + (size_t)(m0 + (ea1 >> 5)) * K + (ea1 & 31);
  const bf16_t* gB0 = B + (size_t)(n0 + (ea0 >> 5)) * K + (ea0 & 31);
  const bf16_t* gB1 = B + (size_t)(n0 + (ea1 >> 5)) * K + (ea1 & 31);
  const bf16_t* gB2 = B + (size_t)(n0 + 128 + (ea0 >> 5)) * K + (ea0 & 31);
  const bf16_t* gB3 = B + (size_t)(n0 + 128 + (ea1 >> 5)) * K + (ea1 & 31);

  auto issue = [&](int s, int koff) {
    async16(&lsA[s][ea0], gA0 + koff);
    async16(&lsA[s][ea1], gA1 + koff);
    async16(&lsB[s][ea0], gB0 + koff);
    async16(&lsB[s][ea1], gB1 + koff);
    async16(&lsB[s][4096 + ea0], gB2 + koff);
    async16(&lsB[s][4096 + ea1], gB3 + koff);
  };
  auto compute = [&](int s) {
    bf16x8 af[4], bfv[8];
#pragma unroll
    for (int i = 0; i < 4; ++i)
      af[i] = *(const bf16x8*)&lsA[s][(wm + i * 16 + r) * 32 + qd * 8];
#pragma unroll
    for (int j = 0; j < 8; ++j)
      bfv[j] = *(const bf16x8*)&lsB[s][(wn + j * 16 + r) * 32 + qd * 8];
#pragma unroll
    for (int mi = 0; mi < 4; ++mi)
#pragma unroll
      for (int ni = 0; ni < 8; ++ni)
        acc[mi][ni] = __builtin_amdgcn_mfma_f32_16x16x32_bf16(
            af[mi], bfv[ni], acc[mi][ni], 0, 0, 0);
  };

  const int ITERS = K / 32;  // 128

  issue(0, 0);
  issue(1, 32);
  __builtin_amdgcn_s_waitcnt(WAIT_VM6_LGKM0);  // stage 0 landed
  __builtin_amdgcn_s_barrier();

  int k = 0;
  const int steady = (ITERS - 2) / 3;  // 42
  for (int j = 0; j < steady; ++j) {
#pragma unroll
    for (int u = 0; u < 3; ++u) {
      issue((u + 2) % 3, (k + 2) * 32);            // stage k+2 in flight
      compute(u);                                  // stage k
      __builtin_amdgcn_s_waitcnt(WAIT_VM6_LGKM0);  // stage k+1 landed
      __builtin_amdgcn_s_barrier();
      ++k;
    }
  }
  // k == ITERS-2; stage (ITERS-2)%3 == 0 ready, final stage in flight.
  compute(0);
  __builtin_amdgcn_s_waitcnt(WAIT_VM0_LGKM0);
  __builtin_amdgcn_s_barrier();
  compute(1);

  // Epilogue: C/D mapping col = lane&15 (n), row = qd*4 + reg (m). fp32 out.
#pragma unroll
  for (int ni = 0; ni < 8; ++ni) {
    const int n = n0 + wn + ni * 16 + r;
    const float bv = bias[n];
#pragma unroll
    for (int mi = 0; mi < 4; ++mi) {
      const int mbase = m0 + wm + mi * 16 + qd * 4;
#pragma unroll
      for (int reg = 0; reg < 4; ++reg) {
        C[(size_t)(mbase + reg) * N + n] = acc[mi][ni][reg] + bv;
      }
    }
  }
}

// ---------------------------------------------------------------------------
// Fallback GEMM (any K%32==0): R5's 128x128 double-buffered version.
// ---------------------------------------------------------------------------
__global__ __launch_bounds__(256) void gemm_db(
    const bf16_t* __restrict__ A, const bf16_t* __restrict__ B,
    const float* __restrict__ bias, float* __restrict__ C, int M, int N,
    int K) {
  __shared__ bf16_t lsA[2][128 * 32];
  __shared__ bf16_t lsB[2][128 * 32];

  const int tid = threadIdx.x;
  const int lane = tid & 63;
  const int wave = tid >> 6;
  const int m0 = blockIdx.y * 128;
  const int n0 = blockIdx.x * 128;
  const int wm = (wave >> 1) * 64;
  const int wn = (wave & 1) * 64;
  const int r = lane & 15;
  const int qd = lane >> 4;

  f32x4 acc[4][4] = {};

  const int e0 = tid * 8;
  const int e1 = 2048 + tid * 8;
  const bf16_t* gA0 = A + (size_t)(m0 + (e0 >> 5)) * K + (e0 & 31);
  const bf16_t* gA1 = A + (size_t)(m0 + (e1 >> 5)) * K + (e1 & 31);
  const bf16_t* gB0 = B + (size_t)(n0 + (e0 >> 5)) * K + (e0 & 31);
  const bf16_t* gB1 = B + (size_t)(n0 + (e1 >> 5)) * K + (e1 & 31);

  async16(&lsA[0][e0], gA0);
  async16(&lsA[0][e1], gA1);
  async16(&lsB[0][e0], gB0);
  async16(&lsB[0][e1], gB1);

  int buf = 0;
  for (int k0 = 0; k0 < K; k0 += 32, buf ^= 1) {
    __syncthreads();
    if (k0 + 32 < K) {
      const int nk = k0 + 32;
      async16(&lsA[buf ^ 1][e0], gA0 + nk);
      async16(&lsA[buf ^ 1][e1], gA1 + nk);
      async16(&lsB[buf ^ 1][e0], gB0 + nk);
      async16(&lsB[buf ^ 1][e1], gB1 + nk);
    }
    bf16x8 af[4], bfv[4];
#pragma unroll
    for (int i = 0; i < 4; ++i) {
      af[i] = *(const bf16x8*)&lsA[buf][(wm + i * 16 + r) * 32 + qd * 8];
      bfv[i] = *(const bf16x8*)&lsB[buf][(wn + i * 16 + r) * 32 + qd * 8];
    }
#pragma unroll
    for (int mi = 0; mi < 4; ++mi)
#pragma unroll
      for (int ni = 0; ni < 4; ++ni)
        acc[mi][ni] = __builtin_amdgcn_mfma_f32_16x16x32_bf16(
            af[mi], bfv[ni], acc[mi][ni], 0, 0, 0);
  }

#pragma unroll
  for (int ni = 0; ni < 4; ++ni) {
    const int n = n0 + wn + ni * 16 + r;
    const float bv = bias[n];
#pragma unroll
    for (int mi = 0; mi < 4; ++mi) {
      const int mbase = m0 + wm + mi * 16 + qd * 4;
#pragma unroll
      for (int reg = 0; reg < 4; ++reg) {
        C[(size_t)(mbase + reg) * N + n] = acc[mi][ni][reg] + bv;
      }
    }
  }
}

// ---------------------------------------------------------------------------
// Fallback (small ws): register-staged GEMM, fused A-convert + B-dequant.
// ---------------------------------------------------------------------------
__global__ __launch_bounds__(256) void gemm_fused(
    const float* __restrict__ Af, const int* __restrict__ q,
    const float* __restrict__ scales, const float* __restrict__ bias,
    float* __restrict__ C, int M, int N, int K, int NB) {
  __shared__ bf16_t lsA[128 * 32];
  __shared__ bf16_t lsB[128 * 32];

  const int tid = threadIdx.x;
  const int lane = tid & 63;
  const int wave = tid >> 6;
  const int m0 = blockIdx.y * 128;
  const int n0 = blockIdx.x * 128;
  const int wm = (wave >> 1) * 64;
  const int wn = (wave & 1) * 64;
  const int r = lane & 15;
  const int qd = lane >> 4;

  const int e = tid * 16;
  const int row = e >> 5;
  const int col = e & 31;

  const float* gAf = Af + (size_t)(m0 + row) * K + col;
  const int* gQ = q + (size_t)(n0 + row) * K + col;
  const float* gS = scales + (size_t)(n0 + row) * NB;

  f32x4 acc[4][4] = {};

  for (int k0 = 0; k0 < K; k0 += 32) {
    bf16x8 a0, a1, b0, b1;
    {
      float4 f0 = *(const float4*)(gAf + k0);
      float4 f1 = *(const float4*)(gAf + k0 + 4);
      float4 f2 = *(const float4*)(gAf + k0 + 8);
      float4 f3 = *(const float4*)(gAf + k0 + 12);
      a0[0] = (bf16_t)f0.x; a0[1] = (bf16_t)f0.y; a0[2] = (bf16_t)f0.z; a0[3] = (bf16_t)f0.w;
      a0[4] = (bf16_t)f1.x; a0[5] = (bf16_t)f1.y; a0[6] = (bf16_t)f1.z; a0[7] = (bf16_t)f1.w;
      a1[0] = (bf16_t)f2.x; a1[1] = (bf16_t)f2.y; a1[2] = (bf16_t)f2.z; a1[3] = (bf16_t)f2.w;
      a1[4] = (bf16_t)f3.x; a1[5] = (bf16_t)f3.y; a1[6] = (bf16_t)f3.z; a1[7] = (bf16_t)f3.w;
    }
    {
      const float s = gS[k0 >> 5];
      int qv[16];
      *(int4*)&qv[0] = *(const int4*)(gQ + k0);
      *(int4*)&qv[4] = *(const int4*)(gQ + k0 + 4);
      *(int4*)&qv[8] = *(const int4*)(gQ + k0 + 8);
      *(int4*)&qv[12] = *(const int4*)(gQ + k0 + 12);
#pragma unroll
      for (int j = 0; j < 8; ++j) b0[j] = (bf16_t)((float)(qv[j] - QOFF) * s);
#pragma unroll
      for (int j = 0; j < 8; ++j)
        b1[j] = (bf16_t)((float)(qv[8 + j] - QOFF) * s);
    }

    __syncthreads();
    *(bf16x8*)&lsA[e] = a0;
    *(bf16x8*)&lsA[e + 8] = a1;
    *(bf16x8*)&lsB[e] = b0;
    *(bf16x8*)&lsB[e + 8] = b1;
    __syncthreads();

    bf16x8 af[4], bfv[4];
#pragma unroll
    for (int i = 0; i < 4; ++i) {
      af[i] = *(const bf16x8*)&lsA[(wm + i * 16 + r) * 32 + qd * 8];
      bfv[i] = *(const bf16x8*)&lsB[(wn + i * 16 + r) * 32 + qd * 8];
    }
#pragma unroll
    for (int mi = 0; mi < 4; ++mi)
#pragma unroll
      for (int ni = 0; ni < 4; ++ni)
        acc[mi][ni] = __builtin_amdgcn_mfma_f32_16x16x32_bf16(
            af[mi], bfv[ni], acc[mi][ni], 0, 0, 0);
  }

#pragma unroll
  for (int ni = 0; ni < 4; ++ni) {
    const int n = n0 + wn + ni * 16 + r;
    const float bv = bias[n];
#pragma unroll
    for (int mi = 0; mi < 4; ++mi) {
      const int mbase = m0 + wm + mi * 16 + qd * 4;
#pragma unroll
      for (int reg = 0; reg < 4; ++reg) {
        C[(size_t)(mbase + reg) * N + n] = acc[mi][ni][reg] + bv;
      }
    }
  }
}

// ---------------------------------------------------------------------------
extern "C" void kernel_launch(void* const* d_in, const int* in_sizes, int n_in,
                              void* d_out, int out_size, void* d_ws,
                              size_t ws_size, hipStream_t stream) {
  const float* x = (const float*)d_in[0];       // [M, K] fp32 (f16 upcast)
  const int* qw = (const int*)d_in[1];          // [O, K] int32
  const float* scales = (const float*)d_in[2];  // [O, NB] fp32
  const float* bias = (const float*)d_in[3];    // [O] fp32
  float* out = (float*)d_out;                   // [M, O] fp32

  const int O = in_sizes[3];       // 4096
  const int K = in_sizes[1] / O;   // 4096
  const int NB = in_sizes[2] / O;  // 128
  const int M = in_sizes[0] / K;   // 4096
  (void)n_in; (void)out_size;

  const size_t Wbytes = (size_t)O * K * sizeof(bf16_t);  // 32 MiB
  const size_t Xbytes = (size_t)M * K * sizeof(bf16_t);  // 32 MiB

  if (ws_size >= Wbytes + Xbytes) {
    bf16_t* W = (bf16_t*)d_ws;
    bf16_t* Xb = (bf16_t*)((char*)d_ws + Wbytes);
    const int nDeq = (int)((size_t)O * K / 2048);
    const int nCvt = (int)((size_t)M * K / 2048);
    prep_kernel<<<nDeq + nCvt, 256, 0, stream>>>(qw, scales, x, W, Xb, K, NB,
                                                 nDeq);
    const int iters = K / 32;
    if (iters >= 5 && (iters - 2) % 3 == 0 && (M % 128) == 0 &&
        (O % 256) == 0) {
      dim3 grid(O / 256, M / 128);
      gemm_pipe2<<<grid, 256, 0, stream>>>(Xb, W, bias, out, M, O, K);
    } else {
      dim3 grid(O / 128, M / 128);
      gemm_db<<<grid, 256, 0, stream>>>(Xb, W, bias, out, M, O, K);
    }
  } else {
    dim3 grid(O / 128, M / 128);
    gemm_fused<<<grid, 256, 0, stream>>>(x, qw, scales, bias, out, M, O, K,
                                         NB);
  }
}